// Round 22
// baseline (153.746 us; speedup 1.0000x reference)
//
#include <hip/hip_runtime.h>

typedef short short8 __attribute__((ext_vector_type(8)));
typedef float f32x4 __attribute__((ext_vector_type(4)));
typedef unsigned long long u64;

#define NE 1024
#define D 64
#define HW 4096
#define MARGIN 3.0e-3f     // t-space margin (proven R3/R5/R12-R21)
#define FLT_MAX_F 3.402823466e+38f
#define MST 33             // mask32 row stride in u32 (pad: conflict-free)

// ws: bn f32[1024]@0 ; ebf u16[65536]@4096
#define WS_BN  0
#define WS_EBF 4096

__device__ __forceinline__ unsigned short f2bf(float f) {   // RNE f32->bf16
    unsigned u = __float_as_uint(f);
    return (unsigned short)((u + 0x7fffu + ((u >> 16) & 1u)) >> 16);
}

// numpy pairwise sum of squares, n=64 (frozen — exact since R2)
__device__ __forceinline__ float np_sum64_sq(const float* v) {
    float s[8];
#pragma unroll
    for (int j = 0; j < 8; ++j) s[j] = __fmul_rn(v[j], v[j]);
#pragma unroll
    for (int i = 8; i < 64; i += 8) {
#pragma unroll
        for (int j = 0; j < 8; ++j)
            s[j] = __fadd_rn(s[j], __fmul_rn(v[i + j], v[i + j]));
    }
    return __fadd_rn(__fadd_rn(__fadd_rn(s[0], s[1]), __fadd_rn(s[2], s[3])),
                     __fadd_rn(__fadd_rn(s[4], s[5]), __fadd_rn(s[6], s[7])));
}

__global__ __launch_bounds__(256) void kP_prep(
        const float* __restrict__ cb, float* __restrict__ bn,
        unsigned short* __restrict__ ebf) {
    const int gid = blockIdx.x * 256 + threadIdx.x;   // 65536 threads
    ebf[gid] = f2bf(cb[gid]);
    if (gid < NE) {
        float row[D];
        const float4* r4 = reinterpret_cast<const float4*>(cb + (size_t)gid * D);
#pragma unroll
        for (int i = 0; i < 16; ++i) {
            float4 v = r4[i];
            row[4*i+0] = v.x; row[4*i+1] = v.y; row[4*i+2] = v.z; row[4*i+3] = v.w;
        }
        bn[gid] = np_sum64_sq(row);
    }
}

// 512 threads / 8 waves, 128 tokens/block, all 1024 codes, SINGLE pass:
// C-init MFMA (-bn/2, R18), register acc stash (R18), chunk-inclusive
// prefix-threshold marks (R19-proven superset), u32 lane-local words (R21),
// R20's double-buffer staging with 1 barrier/phase.
__global__ __launch_bounds__(512, 2) void k_mega(
        const float* __restrict__ in, const unsigned short* __restrict__ ebf,
        const float* __restrict__ bn_g, const float* __restrict__ cb,
        float* __restrict__ out) {
    __shared__ unsigned short ebq[2 * 128 * 64];  // 32 KB double-buffered tile
    __shared__ float sbn[NE];                     // 4 KB  (-0.5*bn)
    __shared__ unsigned mask32[128 * MST];        // 16.9 KB (fully overwritten)
    __shared__ unsigned short win_s[128];

    const int tid  = threadIdx.x;
    const int lane = tid & 63, w = tid >> 6;      // w in 0..7
    const int lcol = lane & 15, lhi = lane >> 4, lrow = lhi * 4;
    const int tokw = blockIdx.x * 128 + w * 16;   // wave's 16 tokens
    const int b = tokw >> 12, hwb = tokw & 4095;

#pragma unroll
    for (int i = 0; i < 2; ++i)
        sbn[tid + i * 512] = __fmul_rn(-0.5f, bn_g[tid + i * 512]);  // exact *0.5

    // B fragments (frozen build, proven R4-R21)
    const float* xbase = in + (size_t)b * (D * HW);
    const int hw0 = hwb + lcol;
    const int kb = lhi * 8;
    short8 B00, B01;
    {
        const float* p;
        p = xbase + (size_t)kb * HW + hw0;
#pragma unroll
        for (int j = 0; j < 8; ++j) B00[j] = (short)f2bf(p[(size_t)j * HW]);
        p = xbase + (size_t)(kb + 32) * HW + hw0;
#pragma unroll
        for (int j = 0; j < 8; ++j) B01[j] = (short)f2bf(p[(size_t)j * HW]);
    }

    const int swz   = (lcol & 7) << 4;
    const int aoff0 = lcol * 128 + ((lhi * 16) ^ swz);
    const int aoff1 = lcol * 128 + ((64 + lhi * 16) ^ swz);

    int4 pf0, pf1;   // prefetch registers (async-split, proven R17-R21)
#define LOADC(C) { const int4* s_ = (const int4*)(ebf + (size_t)(C) * 8192);  \
                   pf0 = s_[tid]; pf1 = s_[tid + 512]; }
#define WRITEC(BUF) { int4 t_[2] = {pf0, pf1};                                \
    _Pragma("unroll")                                                         \
    for (int i = 0; i < 2; ++i) {                                             \
        int L = (tid + i * 512) * 16;                                         \
        int row = L >> 7, wi = L & 127;                                       \
        *(int4*)((char*)ebq + (BUF) * 16384 + row * 128                       \
                 + (wi ^ ((row & 7) << 4))) = t_[i];                          \
    } }

    // ---- single pass: MFMA -> acc stash -> running vmax -> prefix mark ----
    f32x4 vA = {-FLT_MAX_F, -FLT_MAX_F, -FLT_MAX_F, -FLT_MAX_F};
    const int tl = w * 16 + lcol;                 // token-local index (0..127)
    float acc32[32];                              // chunk stash (const-indexed)

    LOADC(0)
    WRITEC(0)
    __syncthreads();
    for (int c = 0; c < 8; ++c) {
        const int buf = c & 1;
        if (c < 7) LOADC(c + 1)
#pragma unroll
        for (int ct = 0; ct < 8; ++ct) {
            const char* lp = (const char*)ebq + buf * 16384 + ct * 2048;
            short8 A0 = *(const short8*)(lp + aoff0);
            short8 A1 = *(const short8*)(lp + aoff1);
            f32x4 acc = *(const f32x4*)(sbn + c * 128 + ct * 16 + lrow);  // C-init
            acc = __builtin_amdgcn_mfma_f32_16x16x32_bf16(A0, B00, acc, 0, 0, 0);
            acc = __builtin_amdgcn_mfma_f32_16x16x32_bf16(A1, B01, acc, 0, 0, 0);
#pragma unroll
            for (int r = 0; r < 4; ++r) {
                acc32[ct * 4 + r] = acc[r];
                vA[r] = fmaxf(vA[r], acc[r]);
            }
        }
        // chunk-inclusive running max across the token's 4 lhi lanes
        float v0 = fmaxf(fmaxf(vA[0], vA[1]), fmaxf(vA[2], vA[3]));
        v0 = fmaxf(v0, __shfl_xor(v0, 16));
        v0 = fmaxf(v0, __shfl_xor(v0, 32));
        const float athr = v0 - 0.5f * MARGIN;   // prefix thr >= final thr - superset
        unsigned m = 0;
#pragma unroll
        for (int ct = 0; ct < 8; ++ct) {
#pragma unroll
            for (int r = 0; r < 4; ++r)
                if (acc32[ct * 4 + r] >= athr) m |= (1u << (ct * 4 + r));
        }
        mask32[tl * MST + c * 4 + lhi] = m;      // lane-local word, no shfl
        if (c < 7) WRITEC(buf ^ 1)
        __syncthreads();
    }

    // ---- rerank: 4 threads/token, frozen-exact, order-independent key min ----
    {
        const int tok_l = tid >> 2, sub = tid & 3;
        const int tok = blockIdx.x * 128 + tok_l;
        const int tb = tok >> 12, thw = tok & 4095;
        const float* x = in + (size_t)tb * (D * HW) + thw;
        float xv[D];
#pragma unroll
        for (int d = 0; d < D; ++d) xv[d] = x[(size_t)d * HW];
        const float a = np_sum64_sq(xv);                      // frozen

        u64 best = ~0ull;
        int kp = -1;
        int pos = 0;
        for (int w32 = 0; w32 < 32; ++w32) {
            unsigned m = mask32[tok_l * MST + w32];
            const int kbase = (w32 >> 2) * 128 + (w32 & 3) * 4;
            while (m) {
                const int bit = (int)__builtin_ctz(m);
                m &= m - 1;
                const int k = kbase + (bit >> 2) * 16 + (bit & 3);
                if (((pos++) & 3) != sub) continue;
                if (kp < 0) { kp = k; continue; }
                // pair: two independent frozen chains (each sequential asc d)
                const float4* e0q = reinterpret_cast<const float4*>(cb + (size_t)kp * D);
                const float4* e1q = reinterpret_cast<const float4*>(cb + (size_t)k * D);
                float d0 = 0.f, d1 = 0.f;
#pragma unroll
                for (int i = 0; i < 16; ++i) {
                    float4 a4 = e0q[i], b4 = e1q[i];
                    float x0 = xv[4*i+0], x1 = xv[4*i+1];
                    float x2 = xv[4*i+2], x3 = xv[4*i+3];
                    d0 = __fmaf_rn(x0, a4.x, d0); d0 = __fmaf_rn(x1, a4.y, d0);
                    d0 = __fmaf_rn(x2, a4.z, d0); d0 = __fmaf_rn(x3, a4.w, d0);
                    d1 = __fmaf_rn(x0, b4.x, d1); d1 = __fmaf_rn(x1, b4.y, d1);
                    d1 = __fmaf_rn(x2, b4.z, d1); d1 = __fmaf_rn(x3, b4.w, d1);
                }
                float q0 = __fsub_rn(__fadd_rn(a, bn_g[kp]), __fmul_rn(2.0f, d0));
                float q1 = __fsub_rn(__fadd_rn(a, bn_g[k]),  __fmul_rn(2.0f, d1));
                u64 key0 = (((u64)__float_as_uint(q0)) << 32) | (unsigned)kp;
                u64 key1 = (((u64)__float_as_uint(q1)) << 32) | (unsigned)k;
                u64 kmin = key0 < key1 ? key0 : key1;
                best = best < kmin ? best : kmin;
                kp = -1;
            }
        }
        if (kp >= 0) {                           // leftover single
            const float4* e0q = reinterpret_cast<const float4*>(cb + (size_t)kp * D);
            float d0 = 0.f;
#pragma unroll
            for (int i = 0; i < 16; ++i) {
                float4 a4 = e0q[i];
                d0 = __fmaf_rn(xv[4*i+0], a4.x, d0);
                d0 = __fmaf_rn(xv[4*i+1], a4.y, d0);
                d0 = __fmaf_rn(xv[4*i+2], a4.z, d0);
                d0 = __fmaf_rn(xv[4*i+3], a4.w, d0);
            }
            float q0 = __fsub_rn(__fadd_rn(a, bn_g[kp]), __fmul_rn(2.0f, d0));
            u64 key0 = (((u64)__float_as_uint(q0)) << 32) | (unsigned)kp;
            best = best < key0 ? best : key0;
        }
#pragma unroll
        for (int o = 1; o < 4; o <<= 1) {        // 4 sub-lanes share a wave
            u64 v = __shfl_xor(best, o);
            best = best < v ? best : v;
        }
        if (sub == 0) win_s[tok_l] = (unsigned short)(best & 0x3FFull);
    }
    __syncthreads();

    // ---- gather: 4 threads/token write the winning codebook row ----
    {
        const int tok_l = tid >> 2, qd = (tid & 3) << 4;
        const int tok = blockIdx.x * 128 + tok_l;
        const int gb = tok >> 12, ghw = tok & 4095;
        const unsigned k = win_s[tok_l];
        const float4* er = reinterpret_cast<const float4*>(cb + (size_t)k * D + qd);
        float* ot = out + (size_t)gb * (D * HW) + ghw;
#pragma unroll
        for (int i = 0; i < 4; ++i) {
            float4 e = er[i];
            ot[(size_t)(qd + 4*i + 0) * HW] = e.x;
            ot[(size_t)(qd + 4*i + 1) * HW] = e.y;
            ot[(size_t)(qd + 4*i + 2) * HW] = e.z;
            ot[(size_t)(qd + 4*i + 3) * HW] = e.w;
        }
    }
}

extern "C" void kernel_launch(void* const* d_in, const int* in_sizes, int n_in,
                              void* d_out, int out_size, void* d_ws, size_t ws_size,
                              hipStream_t stream) {
    const float* in  = (const float*)d_in[0];
    const float* cb  = (const float*)d_in[1];
    float*       out = (float*)d_out;
    char*        ws  = (char*)d_ws;

    float*          bn  = (float*)(ws + WS_BN);
    unsigned short* ebf = (unsigned short*)(ws + WS_EBF);

    hipLaunchKernelGGL(kP_prep, dim3(256), dim3(256), 0, stream, cb, bn, ebf);
    hipLaunchKernelGGL(k_mega,  dim3(512), dim3(512), 0, stream, in, ebf, bn, cb, out);
}

// Round 23
// 105.168 us; speedup vs baseline: 1.4619x; 1.4619x over previous
//
#include <hip/hip_runtime.h>

typedef short short8 __attribute__((ext_vector_type(8)));
typedef float f32x4 __attribute__((ext_vector_type(4)));
typedef unsigned long long u64;

#define NE 1024
#define D 64
#define HW 4096
#define MARGIN 3.0e-3f     // t-space margin (proven R3/R5/R12-R21); acc-space = M/2
#define FLT_MAX_F 3.402823466e+38f
#define MST 33             // mask32 row stride in u32 (pad)

// ws: bn f32[1024]@0 ; ebf u16[65536]@4096
#define WS_BN  0
#define WS_EBF 4096

__device__ __forceinline__ unsigned short f2bf(float f) {   // RNE f32->bf16
    unsigned u = __float_as_uint(f);
    return (unsigned short)((u + 0x7fffu + ((u >> 16) & 1u)) >> 16);
}

// numpy pairwise sum of squares, n=64 (frozen — exact since R2)
__device__ __forceinline__ float np_sum64_sq(const float* v) {
    float s[8];
#pragma unroll
    for (int j = 0; j < 8; ++j) s[j] = __fmul_rn(v[j], v[j]);
#pragma unroll
    for (int i = 8; i < 64; i += 8) {
#pragma unroll
        for (int j = 0; j < 8; ++j)
            s[j] = __fadd_rn(s[j], __fmul_rn(v[i + j], v[i + j]));
    }
    return __fadd_rn(__fadd_rn(__fadd_rn(s[0], s[1]), __fadd_rn(s[2], s[3])),
                     __fadd_rn(__fadd_rn(s[4], s[5]), __fadd_rn(s[6], s[7])));
}

__global__ __launch_bounds__(256) void kP_prep(
        const float* __restrict__ cb, float* __restrict__ bn,
        unsigned short* __restrict__ ebf) {
    const int gid = blockIdx.x * 256 + threadIdx.x;   // 65536 threads
    ebf[gid] = f2bf(cb[gid]);
    if (gid < NE) {
        float row[D];
        const float4* r4 = reinterpret_cast<const float4*>(cb + (size_t)gid * D);
#pragma unroll
        for (int i = 0; i < 16; ++i) {
            float4 v = r4[i];
            row[4*i+0] = v.x; row[4*i+1] = v.y; row[4*i+2] = v.z; row[4*i+3] = v.w;
        }
        bn[gid] = np_sum64_sq(row);
    }
}

// 512 threads / 8 waves, 64 tokens/block. Wave w holds codes [128w,128w+128)
// as A-fragments in REGISTERS; tokens staged once in LDS (swizzled). One
// staging phase, ~6 barriers total. All fragment layouts / MFMA order /
// threshold semantics bit-identical to the proven R18/R20 pipeline.
__global__ __launch_bounds__(512, 4) void k_mega(
        const float* __restrict__ in, const unsigned short* __restrict__ ebf,
        const float* __restrict__ bn_g, const float* __restrict__ cb,
        float* __restrict__ out) {
    __shared__ unsigned short xtile[64 * 64];     // 8 KB token tile (swizzled)
    __shared__ float sbn[NE];                     // 4 KB  (-0.5*bn)
    __shared__ float wmin[8][64];                 // 2 KB per-wave token maxes
    __shared__ float athr_s[64];
    __shared__ unsigned mask32[64 * MST];         // 8.25 KB
    __shared__ unsigned short win_s[64];

    const int tid  = threadIdx.x;
    const int lane = tid & 63, w = tid >> 6;      // w in 0..7 (code slice)
    const int lcol = lane & 15, lhi = lane >> 4, lrow = lhi * 4;
    const int tok0 = blockIdx.x * 64;             // block's 64 tokens
    const int b = tok0 >> 12, hwb = tok0 & 4095;

#pragma unroll
    for (int i = 0; i < 2; ++i)
        sbn[tid + i * 512] = __fmul_rn(-0.5f, bn_g[tid + i * 512]);  // exact *0.5

    // ---- stage 64 tokens -> xtile (bf16, XOR-swizzled rows; frozen f2bf) ----
    {
        // thread i: token row = i>>3, 8 dims starting at (i&7)*8
        const int row = tid >> 3, d0 = (tid & 7) * 8;
        const float* p = in + (size_t)b * (D * HW) + (size_t)d0 * HW + hwb + row;
        short8 v;
#pragma unroll
        for (int j = 0; j < 8; ++j) v[j] = (short)f2bf(p[(size_t)j * HW]);
        const int wi = d0 * 2;                    // byte offset within row
        *(short8*)((char*)xtile + row * 128 + (wi ^ ((row & 7) << 4))) = v;
    }

    // ---- A-fragments: wave w's 128 codes, 16 frags in registers ----
    // af[cg][kh]: lane holds ebf[(128w+cg*16+lcol)*64 + kh*32 + lhi*8 + 0..7]
    short8 af0[8], af1[8];
    {
        const unsigned short* base = ebf + ((size_t)w * 128 + lcol) * 64 + lhi * 8;
#pragma unroll
        for (int cg = 0; cg < 8; ++cg) {
            af0[cg] = *(const short8*)(base + (size_t)cg * 16 * 64);
            af1[cg] = *(const short8*)(base + (size_t)cg * 16 * 64 + 32);
        }
    }
    __syncthreads();

    // B-frag LDS addresses (proven layout + swizzle; row = token)
    // bf[tg][kh]: xtile[tg*16+lcol][kh*32 + lhi*8 .. +7]
#define BFRAG(TG, KH) \
    (*(const short8*)((char*)xtile + (((TG) * 16 + lcol) * 128) + \
        (((KH) * 64 + lhi * 16) ^ ((lcol & 7) << 4))))

    // ---- pass A: 64 MFMAs, in-register max fold, ONE cross-wave merge ----
    float vt0 = -FLT_MAX_F, vt1 = -FLT_MAX_F, vt2 = -FLT_MAX_F, vt3 = -FLT_MAX_F;
#pragma unroll
    for (int tg = 0; tg < 4; ++tg) {
        short8 bA = BFRAG(tg, 0), bB = BFRAG(tg, 1);
        float vt = -FLT_MAX_F;
#pragma unroll
        for (int cg = 0; cg < 8; ++cg) {
            f32x4 acc = *(const f32x4*)(sbn + w * 128 + cg * 16 + lrow);  // C-init
            acc = __builtin_amdgcn_mfma_f32_16x16x32_bf16(af0[cg], bA, acc, 0, 0, 0);
            acc = __builtin_amdgcn_mfma_f32_16x16x32_bf16(af1[cg], bB, acc, 0, 0, 0);
            vt = fmaxf(vt, fmaxf(fmaxf(acc[0], acc[1]), fmaxf(acc[2], acc[3])));
        }
        if (tg == 0) vt0 = vt; else if (tg == 1) vt1 = vt;
        else if (tg == 2) vt2 = vt; else vt3 = vt;
    }
    // cross-lane (4 lhi groups hold different code rows of same token col)
    vt0 = fmaxf(vt0, __shfl_xor(vt0, 16)); vt0 = fmaxf(vt0, __shfl_xor(vt0, 32));
    vt1 = fmaxf(vt1, __shfl_xor(vt1, 16)); vt1 = fmaxf(vt1, __shfl_xor(vt1, 32));
    vt2 = fmaxf(vt2, __shfl_xor(vt2, 16)); vt2 = fmaxf(vt2, __shfl_xor(vt2, 32));
    vt3 = fmaxf(vt3, __shfl_xor(vt3, 16)); vt3 = fmaxf(vt3, __shfl_xor(vt3, 32));
    if (lhi == 0) {
        wmin[w][0 * 16 + lcol] = vt0;
        wmin[w][1 * 16 + lcol] = vt1;
        wmin[w][2 * 16 + lcol] = vt2;
        wmin[w][3 * 16 + lcol] = vt3;
    }
    __syncthreads();

    // global (all-code) acc-space threshold per token: max over 8 waves
    if (tid < 64) {
        float m = wmin[0][tid];
#pragma unroll
        for (int ww = 1; ww < 8; ++ww) m = fmaxf(m, wmin[ww][tid]);
        athr_s[tid] = m - 0.5f * MARGIN;          // t <= tmin+M <=> acc >= max-M/2
    }
    __syncthreads();

    // ---- pass B: bit-identical recompute, u32 lane-local marks ----
#pragma unroll
    for (int tg = 0; tg < 4; ++tg) {
        short8 bA = BFRAG(tg, 0), bB = BFRAG(tg, 1);
        const float athr = athr_s[tg * 16 + lcol];
        unsigned mword = 0;
#pragma unroll
        for (int cg = 0; cg < 8; ++cg) {
            f32x4 acc = *(const f32x4*)(sbn + w * 128 + cg * 16 + lrow);  // C-init
            acc = __builtin_amdgcn_mfma_f32_16x16x32_bf16(af0[cg], bA, acc, 0, 0, 0);
            acc = __builtin_amdgcn_mfma_f32_16x16x32_bf16(af1[cg], bB, acc, 0, 0, 0);
#pragma unroll
            for (int r = 0; r < 4; ++r)
                if (acc[r] >= athr) mword |= (1u << (cg * 4 + r));
        }
        mask32[(tg * 16 + lcol) * MST + w * 4 + lhi] = mword;
    }
    __syncthreads();

    // ---- rerank: 8 threads/token (R13-proven), frozen-exact pair chains ----
    {
        const int tok_l = tid >> 3, sub = tid & 7;
        const int tok = tok0 + tok_l;
        const int tb = tok >> 12, thw = tok & 4095;
        const float* x = in + (size_t)tb * (D * HW) + thw;
        float xv[D];
#pragma unroll
        for (int d = 0; d < D; ++d) xv[d] = x[(size_t)d * HW];
        const float a = np_sum64_sq(xv);                      // frozen

        u64 best = ~0ull;
        int kp = -1;
        int pos = 0;
        for (int ww = 0; ww < 32; ++ww) {
            unsigned m = mask32[tok_l * MST + ww];
            const int kbase = (ww >> 2) * 128 + (ww & 3) * 4;
            while (m) {
                const int bit = (int)__builtin_ctz(m);
                m &= m - 1;
                const int k = kbase + (bit >> 2) * 16 + (bit & 3);
                if (((pos++) & 7) != sub) continue;
                if (kp < 0) { kp = k; continue; }
                // pair: two independent frozen chains (each sequential asc d)
                const float4* e0q = reinterpret_cast<const float4*>(cb + (size_t)kp * D);
                const float4* e1q = reinterpret_cast<const float4*>(cb + (size_t)k * D);
                float d0 = 0.f, d1 = 0.f;
#pragma unroll
                for (int i = 0; i < 16; ++i) {
                    float4 a4 = e0q[i], b4 = e1q[i];
                    float x0 = xv[4*i+0], x1 = xv[4*i+1];
                    float x2 = xv[4*i+2], x3 = xv[4*i+3];
                    d0 = __fmaf_rn(x0, a4.x, d0); d0 = __fmaf_rn(x1, a4.y, d0);
                    d0 = __fmaf_rn(x2, a4.z, d0); d0 = __fmaf_rn(x3, a4.w, d0);
                    d1 = __fmaf_rn(x0, b4.x, d1); d1 = __fmaf_rn(x1, b4.y, d1);
                    d1 = __fmaf_rn(x2, b4.z, d1); d1 = __fmaf_rn(x3, b4.w, d1);
                }
                float q0 = __fsub_rn(__fadd_rn(a, bn_g[kp]), __fmul_rn(2.0f, d0));
                float q1 = __fsub_rn(__fadd_rn(a, bn_g[k]),  __fmul_rn(2.0f, d1));
                u64 key0 = (((u64)__float_as_uint(q0)) << 32) | (unsigned)kp;
                u64 key1 = (((u64)__float_as_uint(q1)) << 32) | (unsigned)k;
                u64 kmin = key0 < key1 ? key0 : key1;
                best = best < kmin ? best : kmin;
                kp = -1;
            }
        }
        if (kp >= 0) {                           // leftover single
            const float4* e0q = reinterpret_cast<const float4*>(cb + (size_t)kp * D);
            float d0 = 0.f;
#pragma unroll
            for (int i = 0; i < 16; ++i) {
                float4 a4 = e0q[i];
                d0 = __fmaf_rn(xv[4*i+0], a4.x, d0);
                d0 = __fmaf_rn(xv[4*i+1], a4.y, d0);
                d0 = __fmaf_rn(xv[4*i+2], a4.z, d0);
                d0 = __fmaf_rn(xv[4*i+3], a4.w, d0);
            }
            float q0 = __fsub_rn(__fadd_rn(a, bn_g[kp]), __fmul_rn(2.0f, d0));
            u64 key0 = (((u64)__float_as_uint(q0)) << 32) | (unsigned)kp;
            best = best < key0 ? best : key0;
        }
#pragma unroll
        for (int o = 1; o < 8; o <<= 1) {        // 8 sub-lanes share a wave
            u64 v = __shfl_xor(best, o);
            best = best < v ? best : v;
        }
        if (sub == 0) win_s[tok_l] = (unsigned short)(best & 0x3FFull);
    }
    __syncthreads();

    // ---- gather: 8 threads/token write the winning codebook row ----
    {
        const int tok_l = tid >> 3, d0 = (tid & 7) * 8;
        const int tok = tok0 + tok_l;
        const int gb = tok >> 12, ghw = tok & 4095;
        const unsigned k = win_s[tok_l];
        const float4* er = reinterpret_cast<const float4*>(cb + (size_t)k * D + d0);
        float* ot = out + (size_t)gb * (D * HW) + ghw;
#pragma unroll
        for (int i = 0; i < 2; ++i) {
            float4 e = er[i];
            ot[(size_t)(d0 + 4*i + 0) * HW] = e.x;
            ot[(size_t)(d0 + 4*i + 1) * HW] = e.y;
            ot[(size_t)(d0 + 4*i + 2) * HW] = e.z;
            ot[(size_t)(d0 + 4*i + 3) * HW] = e.w;
        }
    }
}

extern "C" void kernel_launch(void* const* d_in, const int* in_sizes, int n_in,
                              void* d_out, int out_size, void* d_ws, size_t ws_size,
                              hipStream_t stream) {
    const float* in  = (const float*)d_in[0];
    const float* cb  = (const float*)d_in[1];
    float*       out = (float*)d_out;
    char*        ws  = (char*)d_ws;

    float*          bn  = (float*)(ws + WS_BN);
    unsigned short* ebf = (unsigned short*)(ws + WS_EBF);

    hipLaunchKernelGGL(kP_prep, dim3(256),  dim3(256), 0, stream, cb, bn, ebf);
    hipLaunchKernelGGL(k_mega,  dim3(1024), dim3(512), 0, stream, in, ebf, bn, cb, out);
}